// Round 11
// baseline (2157.801 us; speedup 1.0000x reference)
//
#include <hip/hip_runtime.h>
#include <hip/hip_fp16.h>
#include <stdint.h>

typedef _Float16 f16x8 __attribute__((ext_vector_type(8)));
typedef _Float16 f16x4 __attribute__((ext_vector_type(4)));
typedef float    f32x4 __attribute__((ext_vector_type(4)));

static constexpr int NROWS = 32768;   // b*n
static constexpr int NCODE = 8192;
static constexpr int DDIM  = 512;
static constexpr int BM = 256, BN = 256, BK = 64;
static constexpr int NBM = NROWS / BM;    // 128
static constexpr int NBN = NCODE / BN;    // 32
static constexpr int NPART = NBN * 2;     // 64 partials per row

// out layout (floats): quantize [NROWS*DDIM] | embed_ind [NROWS] | dist [NROWS*NCODE]
static constexpr size_t OFF_IND  = (size_t)NROWS * DDIM;
static constexpr size_t OFF_DIST = OFF_IND + NROWS;

// ws layout (bytes)
static constexpr size_t WS_XH   = 0;
static constexpr size_t WS_XL   = WS_XH + (size_t)NROWS * DDIM * 2;
static constexpr size_t WS_EH   = WS_XL + (size_t)NROWS * DDIM * 2;
static constexpr size_t WS_EL   = WS_EH + (size_t)NCODE * DDIM * 2;
static constexpr size_t WS_X2   = WS_EL + (size_t)NCODE * DDIM * 2;
static constexpr size_t WS_E2   = WS_X2 + (size_t)NROWS * 4;
static constexpr size_t WS_PART = WS_E2 + (size_t)NCODE * 4;

__device__ inline void gload_lds16(const void* g, void* l) {
  __builtin_amdgcn_global_load_lds((const __attribute__((address_space(1))) void*)g,
                                   (__attribute__((address_space(3))) void*)l,
                                   16, 0, 0);
}

// ---------- prep: fp32 -> (f16 hi, f16 lo) split + fp64-accumulated norms ----------
__global__ __launch_bounds__(128)
void prep_kernel(const float* __restrict__ x, const float* __restrict__ e,
                 _Float16* __restrict__ xh, _Float16* __restrict__ xl,
                 _Float16* __restrict__ eh, _Float16* __restrict__ el,
                 float* __restrict__ x2, float* __restrict__ e2)
{
  int bid = blockIdx.x;
  const float* src; _Float16 *dh, *dl; float* nrm;
  if (bid < NROWS) {
    src = x + (size_t)bid * DDIM;
    dh = xh + (size_t)bid * DDIM;  dl = xl + (size_t)bid * DDIM;
    nrm = x2 + bid;
  } else {
    int r = bid - NROWS;
    src = e + (size_t)r * DDIM;
    dh = eh + (size_t)r * DDIM;    dl = el + (size_t)r * DDIM;
    nrm = e2 + r;
  }
  int t = threadIdx.x;
  float4 v = reinterpret_cast<const float4*>(src)[t];
  double s = (double)v.x*v.x + (double)v.y*v.y + (double)v.z*v.z + (double)v.w*v.w;
  f16x4 h, l;
  h.x = (_Float16)v.x; l.x = (_Float16)(v.x - (float)h.x);
  h.y = (_Float16)v.y; l.y = (_Float16)(v.y - (float)h.y);
  h.z = (_Float16)v.z; l.z = (_Float16)(v.z - (float)h.z);
  h.w = (_Float16)v.w; l.w = (_Float16)(v.w - (float)h.w);
  reinterpret_cast<f16x4*>(dh)[t] = h;
  reinterpret_cast<f16x4*>(dl)[t] = l;
  #pragma unroll
  for (int m = 1; m < 64; m <<= 1) s += __shfl_xor(s, m);
  __shared__ double sh[2];
  if ((t & 63) == 0) sh[t >> 6] = s;
  __syncthreads();
  if (t == 0) nrm[0] = (float)(sh[0] + sh[1]);
}

// sync helpers
#define BARx __builtin_amdgcn_s_barrier()
#define VMC(n)  asm volatile("s_waitcnt vmcnt(" #n ")" ::: "memory")

// 16-MFMA cluster, forced inline so array refs dissolve
__device__ __forceinline__ void MMX(f32x4 (&ac)[2][4], const f16x8 (&af)[2][2],
                                    const f16x8 (&bf)[4][2]) {
  __builtin_amdgcn_s_setprio(1);
  #pragma unroll
  for (int m = 0; m < 2; ++m)
    #pragma unroll
    for (int n = 0; n < 4; ++n)
      #pragma unroll
      for (int ks = 0; ks < 2; ++ks)
        ac[m][n] = __builtin_amdgcn_mfma_f32_16x16x32_f16(af[m][ks], bf[n][ks], ac[m][n], 0, 0, 0);
  __builtin_amdgcn_s_setprio(0);
}

// ---------- main: 256x256 split-GEMM, A via LDS, B direct L2->reg ----------
// A halves: h0 = rows 0-127, h2 = rows 128-255 (2 gloads/wave each), BOTH staged into buf b^1.
// B fragments (L2-resident panel via XCD-strip swizzle, L1-shared across waves with equal qwc)
// are loaded global->reg per phase: bf0 in p1, bf1 in p2. 64 KiB LDS total.
// FIFO ledger/wave (steady state, entering p1(t) with 2 outstanding = h2(t)):
//   p1: issue [bf0(t)x8, h0(t+1)x2] -> VMC(2) retires h2(t)+bf0 -> BARx -> LDA reads, MFMA q00,q10
//   p2: issue [bf1(t)x8, h2(t+1)x2] -> VMC(2) retires h0(t+1)+bf1 -> BARx -> MFMA q11,q01
// WAR safety: a region's prior reads are register-consumed (lgkm wait before that phase's MFMAs)
// before the reading wave passes the barrier preceding the overwrite's issue; each write is
// vmcnt-retired + barrier-crossed before its first read.
__global__ __launch_bounds__(512, 1)
void dist_gemm_kernel(const _Float16* __restrict__ xh, const _Float16* __restrict__ xl,
                      const _Float16* __restrict__ eh, const _Float16* __restrict__ el,
                      const float* __restrict__ x2, const float* __restrict__ e2,
                      float* __restrict__ dist, float2* __restrict__ part)
{
  __shared__ _Float16 L[2][BM * BK];   // A only: [buf][256*64] = 64 KiB

  const int tid  = threadIdx.x;
  const int wid  = tid >> 6;
  const int lane = tid & 63;
  const int qwr  = wid >> 1;      // 0..3 : 32-row band within each 128-row half
  const int qwc  = wid & 1;       // 0..1 : 64-col half within each 128-col half

  // Locality swizzle: each XCD owns a fixed 4-wide bn strip (2 MB B panel -> L2-resident).
  const int flat = blockIdx.x;
  const int xcd  = flat & 7;
  const int idx  = flat >> 3;          // 0..511
  const int bn   = xcd * 4 + (idx & 3);
  const int bm   = idx >> 2;           // 0..127
  const int R  = bm * BM;
  const int Cc = bn * BN;

  const int l3 = lane >> 3;
  const int l7 = lane & 7;
  const int srcslot = ((l7 ^ l3) << 4);   // pre-swizzled global 16B-slot (inverse of read swizzle)

  // A staging: half hh (0: rows 0-127, 1: rows 128-255) of tile t into buf nb
  auto STAGE_A = [&](int t, int nb, int hh) {
    const _Float16* base = (t < 16) ? xh : xl;
    const int k0b = (t & 7) * (BK * 2);
    #pragma unroll
    for (int i = 0; i < 2; ++i) {
      const int rr = hh * 128 + wid * 16 + i * 8;
      gload_lds16((const char*)base + (size_t)(R + rr + l3) * (DDIM * 2) + k0b + srcslot,
                  &L[nb][rr * BK]);
    }
  };

  const int l15   = lane & 15;
  const int kslot = (lane >> 4) << 4;     // 0,16,32,48 byte k-slot

  auto LDA = [&](f16x8 (&af)[2][2], int b, int mq) {
    #pragma unroll
    for (int m = 0; m < 2; ++m)
      #pragma unroll
      for (int ks = 0; ks < 2; ++ks) {
        const int row = mq * 128 + qwr * 32 + m * 16 + l15;
        const int kb  = (ks * 64 + kslot) ^ ((row & 7) << 4);
        af[m][ks] = *(const f16x8*)((const char*)&L[b][0] + row * 128 + kb);
      }
  };

  // B direct load: fragment rows Cc + nq*128 + qwc*64 + n*16 + l15, k-bytes k0b + ks*64 + kslot
  auto LDB_G = [&](f16x8 (&bf)[4][2], int t, int nq) {
    const char* base = (const char*)((t < 8 || t >= 16) ? eh : el);
    const char* bp = base + (size_t)(Cc + nq * 128 + qwc * 64 + l15) * (DDIM * 2)
                          + (t & 7) * (BK * 2) + kslot;
    #pragma unroll
    for (int n = 0; n < 4; ++n)
      #pragma unroll
      for (int ks = 0; ks < 2; ++ks)
        bf[n][ks] = *(const f16x8*)(bp + n * 16 * (DDIM * 2) + ks * 64);
  };

  f32x4 acc[2][2][2][4] = {};   // [mq][nq][m][n] = 128 accumulator regs

  // prologue: A h0(0), h2(0) -> buf0 (4 vmem ops outstanding; VMC(2) at p1(0) retires h0,
  // leaving h2(0)x2 = the steady-state invariant)
  STAGE_A(0, 0, 0);
  STAGE_A(0, 0, 1);

  for (int t = 0; t < 23; ++t) {
    const int b = t & 1;
    f16x8 af0[2][2], af1[2][2], bf0[4][2], bf1[4][2];

    // ---- p1: B nq=0 loads + stage A h0(t+1)->buf b^1; VMC(2) confirms h2(t)+bf0 ----
    LDB_G(bf0, t, 0);
    STAGE_A(t + 1, b ^ 1, 0);
    VMC(2);  BARx;
    LDA(af0, b, 0);
    LDA(af1, b, 1);
    MMX(acc[0][0], af0, bf0);
    MMX(acc[1][0], af1, bf0);

    // ---- p2: B nq=1 loads + stage A h2(t+1)->buf b^1; VMC(2) confirms h0(t+1)+bf1 ----
    LDB_G(bf1, t, 1);
    STAGE_A(t + 1, b ^ 1, 1);
    VMC(2);  BARx;
    MMX(acc[1][1], af1, bf1);
    MMX(acc[0][1], af0, bf1);
  }

  // ---- peeled tile 23 (buf1): nothing to stage; exact drains ----
  {
    f16x8 af0[2][2], af1[2][2], bf0[4][2], bf1[4][2];
    LDB_G(bf0, 23, 0);
    VMC(0);  BARx;                 // retires h2(23) + bf0
    LDA(af0, 1, 0);
    LDA(af1, 1, 1);
    MMX(acc[0][0], af0, bf0);
    MMX(acc[1][0], af1, bf0);
    LDB_G(bf1, 23, 1);
    VMC(0);
    MMX(acc[1][1], af1, bf1);
    MMX(acc[0][1], af0, bf1);
  }

  // ---- epilogue: dist + per-wave per-row argmin ----
  const int q    = lane >> 4;
  const int csub = lane & 15;

  float e2v[2][4];
  #pragma unroll
  for (int nq = 0; nq < 2; ++nq)
    #pragma unroll
    for (int n = 0; n < 4; ++n)
      e2v[nq][n] = e2[Cc + nq * 128 + qwc * 64 + n * 16 + csub];

  float bestv[16], besti[16];
  int rix = 0;
  #pragma unroll
  for (int mq = 0; mq < 2; ++mq)
    #pragma unroll
    for (int m = 0; m < 2; ++m)
      #pragma unroll
      for (int j = 0; j < 4; ++j, ++rix) {
        const int row = R + mq * 128 + qwr * 32 + m * 16 + q * 4 + j;
        const float xv = x2[row];
        float* drow = dist + (size_t)row * NCODE;
        float bv = -3.0e38f, bi = 0.0f;
        #pragma unroll
        for (int nq = 0; nq < 2; ++nq)
          #pragma unroll
          for (int n = 0; n < 4; ++n) {
            const int col = Cc + nq * 128 + qwc * 64 + n * 16 + csub;
            float xe = acc[mq][nq][m][n][j];
            float d2 = fmaxf((xv + e2v[nq][n]) - 2.0f * xe, 0.0f);
            float dv = -sqrtf(d2);
            drow[col] = dv;
            if (dv > bv) { bv = dv; bi = (float)col; }     // cols ascending => first-max kept
          }
        bestv[rix] = bv;
        besti[rix] = bi;
      }

  // reduce across the 16 lanes sharing each row
  #pragma unroll
  for (int msk = 1; msk < 16; msk <<= 1) {
    #pragma unroll
    for (int r = 0; r < 16; ++r) {
      float ov = __shfl_xor(bestv[r], msk);
      float oi = __shfl_xor(besti[r], msk);
      if (ov > bestv[r] || (ov == bestv[r] && oi < besti[r])) { bestv[r] = ov; besti[r] = oi; }
    }
  }
  if (csub == 0) {
    int rr = 0;
    #pragma unroll
    for (int mq = 0; mq < 2; ++mq)
      #pragma unroll
      for (int m = 0; m < 2; ++m)
        #pragma unroll
        for (int j = 0; j < 4; ++j, ++rr) {
          const int row = R + mq * 128 + qwr * 32 + m * 16 + q * 4 + j;
          part[(size_t)row * NPART + bn * 2 + qwc] = make_float2(bestv[rr], besti[rr]);
        }
  }
}

// ---------- final: per-row reduce of 64 partials, write index, gather code row ----------
__global__ __launch_bounds__(64)
void reduce_gather_kernel(const float2* __restrict__ part, const float* __restrict__ embed,
                          float* __restrict__ quant, float* __restrict__ ind)
{
  const int row = blockIdx.x;
  const int l = threadIdx.x;
  float2 a = part[(size_t)row * NPART + l];
  float bv = a.x, bi = a.y;
  #pragma unroll
  for (int m = 1; m < 64; m <<= 1) {
    float ov = __shfl_xor(bv, m);
    float oi = __shfl_xor(bi, m);
    if (ov > bv || (ov == bv && oi < bi)) { bv = ov; bi = oi; }
  }
  if (l == 0) ind[row] = bi;
  const int idx = (int)bi;
  const float4* src = reinterpret_cast<const float4*>(embed + (size_t)idx * DDIM);
  float4* dst = reinterpret_cast<float4*>(quant + (size_t)row * DDIM);
  dst[l]      = src[l];
  dst[l + 64] = src[l + 64];
}

extern "C" void kernel_launch(void* const* d_in, const int* in_sizes, int n_in,
                              void* d_out, int out_size, void* d_ws, size_t ws_size,
                              hipStream_t stream) {
  const float* x     = (const float*)d_in[0];
  const float* embed = (const float*)d_in[1];

  char* ws = (char*)d_ws;
  _Float16* xh = (_Float16*)(ws + WS_XH);
  _Float16* xl = (_Float16*)(ws + WS_XL);
  _Float16* eh = (_Float16*)(ws + WS_EH);
  _Float16* el = (_Float16*)(ws + WS_EL);
  float*    x2 = (float*)(ws + WS_X2);
  float*    e2 = (float*)(ws + WS_E2);
  float2*   part = (float2*)(ws + WS_PART);

  float* quant = (float*)d_out;
  float* ind   = (float*)d_out + OFF_IND;
  float* dist  = (float*)d_out + OFF_DIST;

  prep_kernel<<<dim3(NROWS + NCODE), 128, 0, stream>>>(x, embed, xh, xl, eh, el, x2, e2);
  dist_gemm_kernel<<<dim3(NBM * NBN), 512, 0, stream>>>(xh, xl, eh, el, x2, e2, dist, part);
  reduce_gather_kernel<<<dim3(NROWS), 64, 0, stream>>>(part, embed, quant, ind);
}

// Round 12
// 1120.736 us; speedup vs baseline: 1.9253x; 1.9253x over previous
//
#include <hip/hip_runtime.h>
#include <hip/hip_fp16.h>
#include <stdint.h>

typedef _Float16 f16x8 __attribute__((ext_vector_type(8)));
typedef _Float16 f16x4 __attribute__((ext_vector_type(4)));
typedef float    f32x4 __attribute__((ext_vector_type(4)));
typedef float    f32x16 __attribute__((ext_vector_type(16)));

static constexpr int NROWS = 32768;   // b*n
static constexpr int NCODE = 8192;
static constexpr int DDIM  = 512;
static constexpr int BM = 256, BN = 256, BK = 64;
static constexpr int NBM = NROWS / BM;    // 128
static constexpr int NBN = NCODE / BN;    // 32
static constexpr int NPART = NBN * 2;     // 64 partials per row

// out layout (floats): quantize [NROWS*DDIM] | embed_ind [NROWS] | dist [NROWS*NCODE]
static constexpr size_t OFF_IND  = (size_t)NROWS * DDIM;
static constexpr size_t OFF_DIST = OFF_IND + NROWS;

// ws layout (bytes)
static constexpr size_t WS_XH   = 0;
static constexpr size_t WS_XL   = WS_XH + (size_t)NROWS * DDIM * 2;
static constexpr size_t WS_EH   = WS_XL + (size_t)NROWS * DDIM * 2;
static constexpr size_t WS_EL   = WS_EH + (size_t)NCODE * DDIM * 2;
static constexpr size_t WS_X2   = WS_EL + (size_t)NCODE * DDIM * 2;
static constexpr size_t WS_E2   = WS_X2 + (size_t)NROWS * 4;
static constexpr size_t WS_PART = WS_E2 + (size_t)NCODE * 4;

__device__ inline void gload_lds16(const void* g, void* l) {
  __builtin_amdgcn_global_load_lds((const __attribute__((address_space(1))) void*)g,
                                   (__attribute__((address_space(3))) void*)l,
                                   16, 0, 0);
}

// ---------- prep: fp32 -> (f16 hi, f16 lo) split + fp64-accumulated norms ----------
__global__ __launch_bounds__(128)
void prep_kernel(const float* __restrict__ x, const float* __restrict__ e,
                 _Float16* __restrict__ xh, _Float16* __restrict__ xl,
                 _Float16* __restrict__ eh, _Float16* __restrict__ el,
                 float* __restrict__ x2, float* __restrict__ e2)
{
  int bid = blockIdx.x;
  const float* src; _Float16 *dh, *dl; float* nrm;
  if (bid < NROWS) {
    src = x + (size_t)bid * DDIM;
    dh = xh + (size_t)bid * DDIM;  dl = xl + (size_t)bid * DDIM;
    nrm = x2 + bid;
  } else {
    int r = bid - NROWS;
    src = e + (size_t)r * DDIM;
    dh = eh + (size_t)r * DDIM;    dl = el + (size_t)r * DDIM;
    nrm = e2 + r;
  }
  int t = threadIdx.x;
  float4 v = reinterpret_cast<const float4*>(src)[t];
  double s = (double)v.x*v.x + (double)v.y*v.y + (double)v.z*v.z + (double)v.w*v.w;
  f16x4 h, l;
  h.x = (_Float16)v.x; l.x = (_Float16)(v.x - (float)h.x);
  h.y = (_Float16)v.y; l.y = (_Float16)(v.y - (float)h.y);
  h.z = (_Float16)v.z; l.z = (_Float16)(v.z - (float)h.z);
  h.w = (_Float16)v.w; l.w = (_Float16)(v.w - (float)h.w);
  reinterpret_cast<f16x4*>(dh)[t] = h;
  reinterpret_cast<f16x4*>(dl)[t] = l;
  #pragma unroll
  for (int m = 1; m < 64; m <<= 1) s += __shfl_xor(s, m);
  __shared__ double sh[2];
  if ((t & 63) == 0) sh[t >> 6] = s;
  __syncthreads();
  if (t == 0) nrm[0] = (float)(sh[0] + sh[1]);
}

// sync helpers
#define BARx __builtin_amdgcn_s_barrier()
#define VMC(n)  asm volatile("s_waitcnt vmcnt(" #n ")" ::: "memory")

// 16-MFMA cluster (32x32x16): one mq-half x one nq-half (2 c2 x 4 ks)
__device__ __forceinline__ void MMX32(f32x16 (&ac)[2], const f16x8 (&af)[4],
                                      const f16x8 (&bf)[2][4]) {
  __builtin_amdgcn_s_setprio(1);
  #pragma unroll
  for (int c2 = 0; c2 < 2; ++c2)
    #pragma unroll
    for (int ks = 0; ks < 4; ++ks)
      ac[c2] = __builtin_amdgcn_mfma_f32_32x32x16_f16(af[ks], bf[c2][ks], ac[c2], 0, 0, 0);
  __builtin_amdgcn_s_setprio(0);
}

// ---------- main: 256x256 2-phase/tile pipelined split-GEMM, 32x32x16 MFMA ----------
// Staging/ledger identical to the verified r9 kernel (shape-agnostic):
//   halves h0=A rows0-127, h1=B rows0-127, h2=A rows128-255, h3=B rows128-255 (2 gloads/wave each)
//   p1(t): stage h0,h1(t+1)->buf^1; VMC(6) retires h0,h1,h2(t); BARx; MFMA nq=0
//   p2(t): stage h2,h3(t+1)->buf^1; VMC(8) retires h3(t);       BARx; MFMA nq=1
// Fragments (32x32x16): A lane map row=lane&31, k=(lane>>5)*8+e; B symmetric;
// C/D: col=lane&31, row=(reg&3)+8*(reg>>2)+4*(lane>>5)  [HW-verified m74/m101].
__global__ __launch_bounds__(512, 1)
void dist_gemm_kernel(const _Float16* __restrict__ xh, const _Float16* __restrict__ xl,
                      const _Float16* __restrict__ eh, const _Float16* __restrict__ el,
                      const float* __restrict__ x2, const float* __restrict__ e2,
                      float* __restrict__ dist, float2* __restrict__ part)
{
  __shared__ _Float16 L[2][2][BM * BK];   // [buf][A=0/B=1][256*64] = 128 KiB

  const int tid  = threadIdx.x;
  const int wid  = tid >> 6;
  const int lane = tid & 63;
  const int qwr  = wid >> 1;      // 0..3 : 32-row band within each 128-row half
  const int qwc  = wid & 1;       // 0..1 : 64-col half within each 128-col half

  // Locality swizzle: each XCD owns a fixed 4-wide bn strip (2 MB B panel -> L2-resident).
  const int flat = blockIdx.x;
  const int xcd  = flat & 7;
  const int idx  = flat >> 3;          // 0..511
  const int bn   = xcd * 4 + (idx & 3);
  const int bm   = idx >> 2;           // 0..127
  const int R  = bm * BM;
  const int Cc = bn * BN;

  const int l3 = lane >> 3;
  const int l7 = lane & 7;
  const int srcslot = ((l7 ^ l3) << 4);   // pre-swizzled global 16B-slot (inverse of read swizzle)

  auto STAGE_HALF = [&](int t, int nb, int half) {
    const int ab = half & 1;
    const int hh = half >> 1;
    const _Float16* base;
    size_t rowbase;
    if (ab == 0) { base = (t < 16) ? xh : xl;              rowbase = (size_t)R;  }
    else         { base = (t < 8 || t >= 16) ? eh : el;    rowbase = (size_t)Cc; }
    const int k0b = (t & 7) * (BK * 2);
    #pragma unroll
    for (int i = 0; i < 2; ++i) {
      const int rr = hh * 128 + wid * 16 + i * 8;
      gload_lds16((const char*)base + (rowbase + rr + l3) * (DDIM * 2) + k0b + srcslot,
                  &L[nb][ab][rr * BK]);
    }
  };

  const int l31 = lane & 31;
  const int khl = (lane >> 5) * 16;    // 16-byte k-offset for high lane half

  // A fragment set for one mq-half: 4 k-steps, row = mq*128 + qwr*32 + (lane&31)
  auto LDA32 = [&](f16x8 (&af)[4], int b, int mq) {
    const int row = mq * 128 + qwr * 32 + l31;
    const char* base = (const char*)&L[b][0][0] + row * 128;
    #pragma unroll
    for (int ks = 0; ks < 4; ++ks) {
      const int kb = (ks * 32 + khl) ^ ((row & 7) << 4);
      af[ks] = *(const f16x8*)(base + kb);
    }
  };
  // B fragment set for one nq-half: 2 col-frags (c2) x 4 k-steps
  auto LDB32 = [&](f16x8 (&bf)[2][4], int b, int nq) {
    #pragma unroll
    for (int c2 = 0; c2 < 2; ++c2) {
      const int row = nq * 128 + qwc * 64 + c2 * 32 + l31;
      const char* base = (const char*)&L[b][1][0] + row * 128;
      #pragma unroll
      for (int ks = 0; ks < 4; ++ks) {
        const int kb = (ks * 32 + khl) ^ ((row & 7) << 4);
        bf[c2][ks] = *(const f16x8*)(base + kb);
      }
    }
  };

  f32x16 acc[2][2][2] = {};   // [mq][nq][c2] = 8 frags x 16 = 128 accumulator regs

  // prologue: all 4 halves of tile 0 -> buf0 (8 vmem ops)
  STAGE_HALF(0, 0, 0);
  STAGE_HALF(0, 0, 1);
  STAGE_HALF(0, 0, 2);
  STAGE_HALF(0, 0, 3);

  for (int t = 0; t < 23; ++t) {
    const int b = t & 1;
    f16x8 af0[4], af1[4], bfA[2][4], bfB[2][4];

    // ---- p1: stage h0,h1(t+1); VMC(6) confirms h0,h1,h2(t); MFMA nq=0 ----
    STAGE_HALF(t + 1, b ^ 1, 0);
    STAGE_HALF(t + 1, b ^ 1, 1);
    VMC(6);  BARx;
    LDA32(af0, b, 0);
    LDA32(af1, b, 1);
    LDB32(bfA, b, 0);
    MMX32(acc[0][0], af0, bfA);
    MMX32(acc[1][0], af1, bfA);

    // ---- p2: stage h2,h3(t+1); VMC(8) confirms h3(t); MFMA nq=1 ----
    STAGE_HALF(t + 1, b ^ 1, 2);
    STAGE_HALF(t + 1, b ^ 1, 3);
    VMC(8);  BARx;
    LDB32(bfB, b, 1);
    MMX32(acc[1][1], af1, bfB);
    MMX32(acc[0][1], af0, bfB);
  }

  // ---- peeled tile 23 (buf1): nothing left to stage; exact drains ----
  {
    f16x8 af0[4], af1[4], bfA[2][4], bfB[2][4];
    VMC(2);  BARx;                 // retires h0,h1,h2(23)
    LDA32(af0, 1, 0);
    LDA32(af1, 1, 1);
    LDB32(bfA, 1, 0);
    MMX32(acc[0][0], af0, bfA);
    MMX32(acc[1][0], af1, bfA);
    VMC(0);  BARx;                 // retires h3(23)
    LDB32(bfB, 1, 1);
    MMX32(acc[1][1], af1, bfB);
    MMX32(acc[0][1], af0, bfB);
  }

  // ---- epilogue: dist + per-wave per-row argmin (32x32 C/D layout) ----
  const int rhi = (lane >> 5) * 4;   // +4 row offset for lanes 32-63

  float e2v[2][2];
  #pragma unroll
  for (int nq = 0; nq < 2; ++nq)
    #pragma unroll
    for (int c2 = 0; c2 < 2; ++c2)
      e2v[nq][c2] = e2[Cc + nq * 128 + qwc * 64 + c2 * 32 + l31];

  #pragma unroll
  for (int mq = 0; mq < 2; ++mq) {
    float bestv[16], besti[16];
    #pragma unroll
    for (int r = 0; r < 16; ++r) {
      const int row = R + mq * 128 + qwr * 32 + (r & 3) + 8 * (r >> 2) + rhi;
      const float xv = x2[row];
      float* drow = dist + (size_t)row * NCODE;
      float bv = -3.0e38f, bi = 0.0f;
      #pragma unroll
      for (int nq = 0; nq < 2; ++nq)
        #pragma unroll
        for (int c2 = 0; c2 < 2; ++c2) {
          const int col = Cc + nq * 128 + qwc * 64 + c2 * 32 + l31;
          float xe = acc[mq][nq][c2][r];
          float d2 = fmaxf((xv + e2v[nq][c2]) - 2.0f * xe, 0.0f);
          float dv = -sqrtf(d2);
          drow[col] = dv;
          if (dv > bv) { bv = dv; bi = (float)col; }   // per-lane cols ascending => first-max kept
        }
      bestv[r] = bv;
      besti[r] = bi;
    }
    // reduce across the 32 lanes sharing each row set (xor 1..16 stays within lane-half)
    #pragma unroll
    for (int msk = 1; msk < 32; msk <<= 1) {
      #pragma unroll
      for (int r = 0; r < 16; ++r) {
        float ov = __shfl_xor(bestv[r], msk);
        float oi = __shfl_xor(besti[r], msk);
        if (ov > bestv[r] || (ov == bestv[r] && oi < besti[r])) { bestv[r] = ov; besti[r] = oi; }
      }
    }
    if (l31 == 0) {
      #pragma unroll
      for (int r = 0; r < 16; ++r) {
        const int row = R + mq * 128 + qwr * 32 + (r & 3) + 8 * (r >> 2) + rhi;
        part[(size_t)row * NPART + bn * 2 + qwc] = make_float2(bestv[r], besti[r]);
      }
    }
  }
}

// ---------- final: per-row reduce of 64 partials, write index, gather code row ----------
__global__ __launch_bounds__(64)
void reduce_gather_kernel(const float2* __restrict__ part, const float* __restrict__ embed,
                          float* __restrict__ quant, float* __restrict__ ind)
{
  const int row = blockIdx.x;
  const int l = threadIdx.x;
  float2 a = part[(size_t)row * NPART + l];
  float bv = a.x, bi = a.y;
  #pragma unroll
  for (int m = 1; m < 64; m <<= 1) {
    float ov = __shfl_xor(bv, m);
    float oi = __shfl_xor(bi, m);
    if (ov > bv || (ov == bv && oi < bi)) { bv = ov; bi = oi; }
  }
  if (l == 0) ind[row] = bi;
  const int idx = (int)bi;
  const float4* src = reinterpret_cast<const float4*>(embed + (size_t)idx * DDIM);
  float4* dst = reinterpret_cast<float4*>(quant + (size_t)row * DDIM);
  dst[l]      = src[l];
  dst[l + 64] = src[l + 64];
}

extern "C" void kernel_launch(void* const* d_in, const int* in_sizes, int n_in,
                              void* d_out, int out_size, void* d_ws, size_t ws_size,
                              hipStream_t stream) {
  const float* x     = (const float*)d_in[0];
  const float* embed = (const float*)d_in[1];

  char* ws = (char*)d_ws;
  _Float16* xh = (_Float16*)(ws + WS_XH);
  _Float16* xl = (_Float16*)(ws + WS_XL);
  _Float16* eh = (_Float16*)(ws + WS_EH);
  _Float16* el = (_Float16*)(ws + WS_EL);
  float*    x2 = (float*)(ws + WS_X2);
  float*    e2 = (float*)(ws + WS_E2);
  float2*   part = (float2*)(ws + WS_PART);

  float* quant = (float*)d_out;
  float* ind   = (float*)d_out + OFF_IND;
  float* dist  = (float*)d_out + OFF_DIST;

  prep_kernel<<<dim3(NROWS + NCODE), 128, 0, stream>>>(x, embed, xh, xl, eh, el, x2, e2);
  dist_gemm_kernel<<<dim3(NBM * NBN), 512, 0, stream>>>(xh, xl, eh, el, x2, e2, dist, part);
  reduce_gather_kernel<<<dim3(NROWS), 64, 0, stream>>>(part, embed, quant, ind);
}

// Round 13
// 944.391 us; speedup vs baseline: 2.2849x; 1.1867x over previous
//
#include <hip/hip_runtime.h>
#include <hip/hip_fp16.h>
#include <stdint.h>

typedef _Float16 f16x8 __attribute__((ext_vector_type(8)));
typedef _Float16 f16x4 __attribute__((ext_vector_type(4)));
typedef float    f32x4 __attribute__((ext_vector_type(4)));

static constexpr int NROWS = 32768;   // b*n
static constexpr int NCODE = 8192;
static constexpr int DDIM  = 512;
static constexpr int BM = 256, BN = 256, BK = 64;
static constexpr int NBM = NROWS / BM;    // 128
static constexpr int NBN = NCODE / BN;    // 32
static constexpr int NPART = NBN * 2;     // 64 partials per row

// out layout (floats): quantize [NROWS*DDIM] | embed_ind [NROWS] | dist [NROWS*NCODE]
static constexpr size_t OFF_IND  = (size_t)NROWS * DDIM;
static constexpr size_t OFF_DIST = OFF_IND + NROWS;

// ws layout (bytes)
static constexpr size_t WS_XH   = 0;
static constexpr size_t WS_XL   = WS_XH + (size_t)NROWS * DDIM * 2;
static constexpr size_t WS_EH   = WS_XL + (size_t)NROWS * DDIM * 2;
static constexpr size_t WS_EL   = WS_EH + (size_t)NCODE * DDIM * 2;
static constexpr size_t WS_X2   = WS_EL + (size_t)NCODE * DDIM * 2;
static constexpr size_t WS_E2   = WS_X2 + (size_t)NROWS * 4;
static constexpr size_t WS_PART = WS_E2 + (size_t)NCODE * 4;

__device__ inline void gload_lds16(const void* g, void* l) {
  __builtin_amdgcn_global_load_lds((const __attribute__((address_space(1))) void*)g,
                                   (__attribute__((address_space(3))) void*)l,
                                   16, 0, 0);
}

// ---------- prep: fp32 -> (f16 hi, f16 lo) split + fp64-accumulated norms ----------
__global__ __launch_bounds__(128)
void prep_kernel(const float* __restrict__ x, const float* __restrict__ e,
                 _Float16* __restrict__ xh, _Float16* __restrict__ xl,
                 _Float16* __restrict__ eh, _Float16* __restrict__ el,
                 float* __restrict__ x2, float* __restrict__ e2)
{
  int bid = blockIdx.x;
  const float* src; _Float16 *dh, *dl; float* nrm;
  if (bid < NROWS) {
    src = x + (size_t)bid * DDIM;
    dh = xh + (size_t)bid * DDIM;  dl = xl + (size_t)bid * DDIM;
    nrm = x2 + bid;
  } else {
    int r = bid - NROWS;
    src = e + (size_t)r * DDIM;
    dh = eh + (size_t)r * DDIM;    dl = el + (size_t)r * DDIM;
    nrm = e2 + r;
  }
  int t = threadIdx.x;
  float4 v = reinterpret_cast<const float4*>(src)[t];
  double s = (double)v.x*v.x + (double)v.y*v.y + (double)v.z*v.z + (double)v.w*v.w;
  f16x4 h, l;
  h.x = (_Float16)v.x; l.x = (_Float16)(v.x - (float)h.x);
  h.y = (_Float16)v.y; l.y = (_Float16)(v.y - (float)h.y);
  h.z = (_Float16)v.z; l.z = (_Float16)(v.z - (float)h.z);
  h.w = (_Float16)v.w; l.w = (_Float16)(v.w - (float)h.w);
  reinterpret_cast<f16x4*>(dh)[t] = h;
  reinterpret_cast<f16x4*>(dl)[t] = l;
  #pragma unroll
  for (int m = 1; m < 64; m <<= 1) s += __shfl_xor(s, m);
  __shared__ double sh[2];
  if ((t & 63) == 0) sh[t >> 6] = s;
  __syncthreads();
  if (t == 0) nrm[0] = (float)(sh[0] + sh[1]);
}

// sync helpers
#define BARx __builtin_amdgcn_s_barrier()
#define VMC(n)  asm volatile("s_waitcnt vmcnt(" #n ")" ::: "memory")

// 16-MFMA cluster, forced inline so array refs dissolve
__device__ __forceinline__ void MMX(f32x4 (&ac)[2][4], const f16x8 (&af)[2][2],
                                    const f16x8 (&bf)[4][2]) {
  __builtin_amdgcn_s_setprio(1);
  #pragma unroll
  for (int m = 0; m < 2; ++m)
    #pragma unroll
    for (int n = 0; n < 4; ++n)
      #pragma unroll
      for (int ks = 0; ks < 2; ++ks)
        ac[m][n] = __builtin_amdgcn_mfma_f32_16x16x32_f16(af[m][ks], bf[n][ks], ac[m][n], 0, 0, 0);
  __builtin_amdgcn_s_setprio(0);
}

// ---------- main: 256x256 4-phase/tile, m201-ordered (reads PRE-barrier) split-GEMM ----------
// Halves: h0=A rows0-127, h1=B rows0-127, h2=A rows128-255, h3=B rows128-255 (2 gloads/wave each).
// Stage stream: p1:h1(t+1) p2:h2(t+1) p3:h3(t+1) p4:h0(t+2).  vmcnt(6) at p1,p2,p4; none at p3.
// m201 phase order: ds_read frags for THIS phase (data retired >=1 barrier ago) -> stage ->
// vmcnt -> barrier -> MFMA.  Reads fly during barrier-wait and under other waves' MFMAs;
// frag live ranges end at the same phase's MFMA (no cross-tile carrying -> no register cliff).
// Retirement proof (FIFO, steady state Q entering p1 = [h2(t),h3(t),h0(t+1)] = 6):
//   p1 reads h0,h1(t): retired @p4(t-1) VMC(6)+bar.  p2 reads h2(t): @p1 VMC(6)+bar.
//   p3 reads h3(t): @p2 VMC(6)+bar.  p4: no reads.
__global__ __launch_bounds__(512, 1)
void dist_gemm_kernel(const _Float16* __restrict__ xh, const _Float16* __restrict__ xl,
                      const _Float16* __restrict__ eh, const _Float16* __restrict__ el,
                      const float* __restrict__ x2, const float* __restrict__ e2,
                      float* __restrict__ dist, float2* __restrict__ part)
{
  __shared__ _Float16 L[2][2][BM * BK];   // [buf][A=0/B=1][256*64] = 128 KiB

  const int tid  = threadIdx.x;
  const int wid  = tid >> 6;
  const int lane = tid & 63;
  const int qwr  = wid >> 1;      // 0..3 : 32-row band within each 128-row half
  const int qwc  = wid & 1;       // 0..1 : 64-col half within each 128-col half

  // Locality swizzle: each XCD owns a fixed 4-wide bn strip (2 MB B panel -> L2-resident).
  const int flat = blockIdx.x;
  const int xcd  = flat & 7;
  const int idx  = flat >> 3;          // 0..511
  const int bn   = xcd * 4 + (idx & 3);
  const int bm   = idx >> 2;           // 0..127
  const int R  = bm * BM;
  const int Cc = bn * BN;

  const int l3 = lane >> 3;
  const int l7 = lane & 7;
  const int srcslot = ((l7 ^ l3) << 4);   // pre-swizzled global 16B-slot (inverse of read swizzle)

  auto STAGE_HALF = [&](int t, int nb, int half) {
    const int ab = half & 1;
    const int hh = half >> 1;
    const _Float16* base;
    size_t rowbase;
    if (ab == 0) { base = (t < 16) ? xh : xl;              rowbase = (size_t)R;  }
    else         { base = (t < 8 || t >= 16) ? eh : el;    rowbase = (size_t)Cc; }
    const int k0b = (t & 7) * (BK * 2);
    #pragma unroll
    for (int i = 0; i < 2; ++i) {
      const int rr = hh * 128 + wid * 16 + i * 8;
      gload_lds16((const char*)base + (rowbase + rr + l3) * (DDIM * 2) + k0b + srcslot,
                  &L[nb][ab][rr * BK]);
    }
  };

  const int l15   = lane & 15;
  const int kslot = (lane >> 4) << 4;     // 0,16,32,48 byte k-slot

  auto LDA = [&](f16x8 (&af)[2][2], int b, int mq) {
    #pragma unroll
    for (int m = 0; m < 2; ++m)
      #pragma unroll
      for (int ks = 0; ks < 2; ++ks) {
        const int row = mq * 128 + qwr * 32 + m * 16 + l15;
        const int kb  = (ks * 64 + kslot) ^ ((row & 7) << 4);
        af[m][ks] = *(const f16x8*)((const char*)&L[b][0][0] + row * 128 + kb);
      }
  };
  auto LDB = [&](f16x8 (&bf)[4][2], int b, int nq) {
    #pragma unroll
    for (int n = 0; n < 4; ++n)
      #pragma unroll
      for (int ks = 0; ks < 2; ++ks) {
        const int row = nq * 128 + qwc * 64 + n * 16 + l15;
        const int kb  = (ks * 64 + kslot) ^ ((row & 7) << 4);
        bf[n][ks] = *(const f16x8*)((const char*)&L[b][1][0] + row * 128 + kb);
      }
  };

  f32x4 acc[2][2][2][4] = {};   // [mq][nq][m][n] = 128 accumulator regs

  // prologue: h0..h3(0)->buf0, h0(1)->buf1 = 10 vmem ops; VMC(6) retires h0,h1(0).
  STAGE_HALF(0, 0, 0);
  STAGE_HALF(0, 0, 1);
  STAGE_HALF(0, 0, 2);
  STAGE_HALF(0, 0, 3);
  STAGE_HALF(1, 1, 0);
  VMC(6);
  BARx;

  for (int t = 0; t < 22; ++t) {
    const int b = t & 1;
    f16x8 af0[2][2], af1[2][2], bf0[4][2], bf1[4][2];

    // p1: reads h0,h1(t) [retired @p4(t-1)/prologue] PRE-barrier; stage h1(t+1); MFMA q00
    LDA(af0, b, 0);
    LDB(bf0, b, 0);
    STAGE_HALF(t + 1, b ^ 1, 1);
    VMC(6);  BARx;                      // retires h2(t)
    MMX(acc[0][0], af0, bf0);

    // p2: read h2(t) [retired @p1] PRE-barrier; stage h2(t+1); MFMA q10
    LDA(af1, b, 1);
    STAGE_HALF(t + 1, b ^ 1, 2);
    VMC(6);  BARx;                      // retires h3(t)
    MMX(acc[1][0], af1, bf0);

    // p3: read h3(t) [retired @p2] PRE-barrier; stage h3(t+1); MFMA q11
    LDB(bf1, b, 1);
    STAGE_HALF(t + 1, b ^ 1, 3);
    BARx;
    MMX(acc[1][1], af1, bf1);

    // p4: no reads; stage h0(t+2) into current buf (region last read @p1, 3 barriers ago)
    STAGE_HALF(t + 2, b, 0);
    VMC(6);  BARx;                      // retires h0(t+1),h1(t+1)
    MMX(acc[0][1], af0, bf1);
  }

  // ---- peeled tile 22 (buf0): stages only h1..h3(23) ----
  {
    f16x8 af0[2][2], af1[2][2], bf0[4][2], bf1[4][2];
    LDA(af0, 0, 0);
    LDB(bf0, 0, 0);
    STAGE_HALF(23, 1, 1);
    VMC(6);  BARx;
    MMX(acc[0][0], af0, bf0);
    LDA(af1, 0, 1);
    STAGE_HALF(23, 1, 2);
    VMC(6);  BARx;
    MMX(acc[1][0], af1, bf0);
    LDB(bf1, 0, 1);
    STAGE_HALF(23, 1, 3);
    BARx;
    MMX(acc[1][1], af1, bf1);
    VMC(4);  BARx;                      // retires h0(23),h1(23)
    MMX(acc[0][1], af0, bf1);
  }
  // ---- peeled tile 23 (buf1): drain ----
  {
    f16x8 af0[2][2], af1[2][2], bf0[4][2], bf1[4][2];
    LDA(af0, 1, 0);
    LDB(bf0, 1, 0);
    VMC(2);  BARx;                      // retires h2(23)
    LDA(af1, 1, 1);
    MMX(acc[0][0], af0, bf0);
    MMX(acc[1][0], af1, bf0);
    VMC(0);  BARx;                      // retires h3(23)
    LDB(bf1, 1, 1);
    MMX(acc[1][1], af1, bf1);
    MMX(acc[0][1], af0, bf1);
  }

  // ---- epilogue: dist + per-wave per-row argmin ----
  const int q    = lane >> 4;
  const int csub = lane & 15;

  float e2v[2][4];
  #pragma unroll
  for (int nq = 0; nq < 2; ++nq)
    #pragma unroll
    for (int n = 0; n < 4; ++n)
      e2v[nq][n] = e2[Cc + nq * 128 + qwc * 64 + n * 16 + csub];

  float bestv[16], besti[16];
  int rix = 0;
  #pragma unroll
  for (int mq = 0; mq < 2; ++mq)
    #pragma unroll
    for (int m = 0; m < 2; ++m)
      #pragma unroll
      for (int j = 0; j < 4; ++j, ++rix) {
        const int row = R + mq * 128 + qwr * 32 + m * 16 + q * 4 + j;
        const float xv = x2[row];
        float* drow = dist + (size_t)row * NCODE;
        float bv = -3.0e38f, bi = 0.0f;
        #pragma unroll
        for (int nq = 0; nq < 2; ++nq)
          #pragma unroll
          for (int n = 0; n < 4; ++n) {
            const int col = Cc + nq * 128 + qwc * 64 + n * 16 + csub;
            float xe = acc[mq][nq][m][n][j];
            float d2 = fmaxf((xv + e2v[nq][n]) - 2.0f * xe, 0.0f);
            float dv = -sqrtf(d2);
            drow[col] = dv;
            if (dv > bv) { bv = dv; bi = (float)col; }     // cols ascending => first-max kept
          }
        bestv[rix] = bv;
        besti[rix] = bi;
      }

  // reduce across the 16 lanes sharing each row
  #pragma unroll
  for (int msk = 1; msk < 16; msk <<= 1) {
    #pragma unroll
    for (int r = 0; r < 16; ++r) {
      float ov = __shfl_xor(bestv[r], msk);
      float oi = __shfl_xor(besti[r], msk);
      if (ov > bestv[r] || (ov == bestv[r] && oi < besti[r])) { bestv[r] = ov; besti[r] = oi; }
    }
  }
  if (csub == 0) {
    int rr = 0;
    #pragma unroll
    for (int mq = 0; mq < 2; ++mq)
      #pragma unroll
      for (int m = 0; m < 2; ++m)
        #pragma unroll
        for (int j = 0; j < 4; ++j, ++rr) {
          const int row = R + mq * 128 + qwr * 32 + m * 16 + q * 4 + j;
          part[(size_t)row * NPART + bn * 2 + qwc] = make_float2(bestv[rr], besti[rr]);
        }
  }
}

// ---------- final: per-row reduce of 64 partials, write index, gather code row ----------
__global__ __launch_bounds__(64)
void reduce_gather_kernel(const float2* __restrict__ part, const float* __restrict__ embed,
                          float* __restrict__ quant, float* __restrict__ ind)
{
  const int row = blockIdx.x;
  const int l = threadIdx.x;
  float2 a = part[(size_t)row * NPART + l];
  float bv = a.x, bi = a.y;
  #pragma unroll
  for (int m = 1; m < 64; m <<= 1) {
    float ov = __shfl_xor(bv, m);
    float oi = __shfl_xor(bi, m);
    if (ov > bv || (ov == bv && oi < bi)) { bv = ov; bi = oi; }
  }
  if (l == 0) ind[row] = bi;
  const int idx = (int)bi;
  const float4* src = reinterpret_cast<const float4*>(embed + (size_t)idx * DDIM);
  float4* dst = reinterpret_cast<float4*>(quant + (size_t)row * DDIM);
  dst[l]      = src[l];
  dst[l + 64] = src[l + 64];
}

extern "C" void kernel_launch(void* const* d_in, const int* in_sizes, int n_in,
                              void* d_out, int out_size, void* d_ws, size_t ws_size,
                              hipStream_t stream) {
  const float* x     = (const float*)d_in[0];
  const float* embed = (const float*)d_in[1];

  char* ws = (char*)d_ws;
  _Float16* xh = (_Float16*)(ws + WS_XH);
  _Float16* xl = (_Float16*)(ws + WS_XL);
  _Float16* eh = (_Float16*)(ws + WS_EH);
  _Float16* el = (_Float16*)(ws + WS_EL);
  float*    x2 = (float*)(ws + WS_X2);
  float*    e2 = (float*)(ws + WS_E2);
  float2*   part = (float2*)(ws + WS_PART);

  float* quant = (float*)d_out;
  float* ind   = (float*)d_out + OFF_IND;
  float* dist  = (float*)d_out + OFF_DIST;

  prep_kernel<<<dim3(NROWS + NCODE), 128, 0, stream>>>(x, embed, xh, xl, eh, el, x2, e2);
  dist_gemm_kernel<<<dim3(NBM * NBN), 512, 0, stream>>>(xh, xl, eh, el, x2, e2, dist, part);
  reduce_gather_kernel<<<dim3(NROWS), 64, 0, stream>>>(part, embed, quant, ind);
}